// Round 2
// baseline (521.513 us; speedup 1.0000x reference)
//
#include <hip/hip_runtime.h>
#include <hip/hip_bf16.h>

#pragma clang fp contract(off)

#define NB 8
#define NG 64
#define NA 33600
#define KTOP 9
#define NCAND 27
#define NPRO 31
#define NALP 24
#define NADS 37
#define S0 268800  // NB*NA

// _pairwise_iou semantics: unclipped areas, union = max(a1+a2-ov, 1e-6)
__device__ __forceinline__ float pair_iou(float x1, float y1, float x2, float y2,
                                          float ax1, float ay1, float ax2, float ay2) {
    float a1 = (x2 - x1) * (y2 - y1);
    float a2 = (ax2 - ax1) * (ay2 - ay1);
    float w = fminf(x2, ax2) - fmaxf(x1, ax1); w = fmaxf(w, 0.0f);
    float h = fminf(y2, ay2) - fmaxf(y1, ay1); h = fmaxf(h, 0.0f);
    float ov = w * h;
    float un = a1 + a2 - ov; un = fmaxf(un, 1e-6f);
    return ov / un;
}

__global__ __launch_bounds__(256) void k_zero_gbits(unsigned long long* __restrict__ g) {
    int t = blockIdx.x * 256 + threadIdx.x;
    if (t < S0) g[t] = 0ull;
}

// Kernel 1: one block per (b,g). Top-9 per level by (distance, index) lex order,
// ATSS threshold, set bit g in gbits[b*NA + a] for each positive anchor.
__global__ __launch_bounds__(256) void k_cand(
    const float* __restrict__ anc,     // NA x 4
    const float* __restrict__ gt,      // NB x NG x 4
    const float* __restrict__ mgt,     // NB x NG
    unsigned long long* __restrict__ gbits) // NB x NA
{
    int bg = blockIdx.x;
    int b = bg >> 6;
    int g = bg & 63;
    if (mgt[bg] <= 0.0f) return;

    const float x1 = gt[bg * 4 + 0], y1 = gt[bg * 4 + 1];
    const float x2 = gt[bg * 4 + 2], y2 = gt[bg * 4 + 3];
    const float gx = (x1 + x2) * 0.5f, gy = (y1 + y2) * 0.5f;

    __shared__ float sd[256][KTOP];
    __shared__ int   si[256][KTOP];
    __shared__ int   cand[NCAND];

    const int tid = threadIdx.x;
    const int starts[3] = {0, 25600, 32000};
    const int lens[3]   = {25600, 6400, 1600};

    for (int lev = 0; lev < 3; ++lev) {
        float d9[KTOP]; int i9[KTOP];
        #pragma unroll
        for (int j = 0; j < KTOP; ++j) { d9[j] = INFINITY; i9[j] = 0x7fffffff; }

        const int s = starts[lev], L = lens[lev];
        for (int li = tid; li < L; li += 256) {
            int a = s + li;
            float ax = (anc[a * 4 + 0] + anc[a * 4 + 2]) * 0.5f;
            float ay = (anc[a * 4 + 1] + anc[a * 4 + 3]) * 0.5f;
            float dx = gx - ax, dy = gy - ay;
            float d = sqrtf(dx * dx + dy * dy);
            if (d < d9[KTOP - 1] || (d == d9[KTOP - 1] && li < i9[KTOP - 1])) {
                int j = KTOP - 1;
                while (j > 0 && (d < d9[j - 1] || (d == d9[j - 1] && li < i9[j - 1]))) {
                    d9[j] = d9[j - 1]; i9[j] = i9[j - 1]; --j;
                }
                d9[j] = d; i9[j] = li;
            }
        }

        for (int off = 128; off >= 1; off >>= 1) {
            #pragma unroll
            for (int j = 0; j < KTOP; ++j) { sd[tid][j] = d9[j]; si[tid][j] = i9[j]; }
            __syncthreads();
            if (tid < off) {
                float md[KTOP]; int mi[KTOP];
                int p = 0, q = 0;
                #pragma unroll
                for (int j = 0; j < KTOP; ++j) {
                    float da = d9[p];            int ia = i9[p];
                    float db = sd[tid + off][q]; int ib = si[tid + off][q];
                    bool takeA = (da < db) || (da == db && ia <= ib);
                    if (takeA) { md[j] = da; mi[j] = ia; ++p; }
                    else       { md[j] = db; mi[j] = ib; ++q; }
                }
                #pragma unroll
                for (int j = 0; j < KTOP; ++j) { d9[j] = md[j]; i9[j] = mi[j]; }
            }
            __syncthreads();
        }
        if (tid == 0) {
            #pragma unroll
            for (int j = 0; j < KTOP; ++j) cand[lev * KTOP + j] = s + i9[j];
        }
        __syncthreads();
    }

    if (tid == 0) {
        float co[NCAND];
        float sum = 0.0f;
        for (int j = 0; j < NCAND; ++j) {
            int a = cand[j];
            co[j] = pair_iou(x1, y1, x2, y2,
                             anc[a * 4 + 0], anc[a * 4 + 1], anc[a * 4 + 2], anc[a * 4 + 3]);
            sum += co[j];
        }
        float m = sum / 27.0f;
        float v = 0.0f;
        for (int j = 0; j < NCAND; ++j) { float dd = co[j] - m; v += dd * dd; }
        float thr = m + sqrtf(v / 26.0f);  // ddof=1
        for (int j = 0; j < NCAND; ++j) {
            if (co[j] > thr) {
                int a = cand[j];
                float ax = (anc[a * 4 + 0] + anc[a * 4 + 2]) * 0.5f;
                float ay = (anc[a * 4 + 1] + anc[a * 4 + 3]) * 0.5f;
                float mn = fminf(fminf(ax - x1, ay - y1), fminf(x2 - ax, y2 - ay));
                if (mn > 1e-9f) {
                    atomicOr(&gbits[(unsigned long long)b * NA + a], 1ull << g);
                }
            }
        }
    }
}

// Kernel 2: one thread per (b,anchor). Resolve multi-assignment, write the 20
// target planes + fg plane densely, and emit per-anchor (iou*fg, packed cls)
// records for the score-writer kernel.
__global__ __launch_bounds__(256) void k_assign(
    const float* __restrict__ anc,
    const float* __restrict__ gt_pro,
    const float* __restrict__ gt_alp,
    const float* __restrict__ gt_ads,
    const float* __restrict__ gt,
    const float* __restrict__ gt_cn,
    const float* __restrict__ pd,
    const unsigned long long* __restrict__ gbits,
    float* __restrict__ iou_fg,            // S0
    unsigned long long* __restrict__ cls8, // S0
    float* __restrict__ out)
{
    const int t = blockIdx.x * 256 + threadIdx.x;
    if (t >= S0) return;
    const int b = t / NA;
    const int a = t - b * NA;

    unsigned long long m = gbits[t];
    if (__popcll(m) > 1) {
        float ax1 = anc[a * 4 + 0], ay1 = anc[a * 4 + 1];
        float ax2 = anc[a * 4 + 2], ay2 = anc[a * 4 + 3];
        float aarea = (ax2 - ax1) * (ay2 - ay1);
        float best = -INFINITY; int bgi = 0;
        for (int g = 0; g < NG; ++g) {
            const float* G = gt + ((size_t)b * NG + g) * 4;
            float gx1 = G[0], gy1 = G[1], gx2 = G[2], gy2 = G[3];
            float a1 = (gx2 - gx1) * (gy2 - gy1);
            float w = fminf(gx2, ax2) - fmaxf(gx1, ax1); w = fmaxf(w, 0.0f);
            float h = fminf(gy2, ay2) - fmaxf(gy1, ay1); h = fmaxf(h, 0.0f);
            float ov = w * h;
            float un = a1 + aarea - ov; un = fmaxf(un, 1e-6f);
            float iou = ov / un;
            if (iou > best) { best = iou; bgi = g; }
        }
        m = 1ull << bgi;
    }
    const bool fgb = (m != 0ull);
    const int tg = fgb ? (__ffsll((unsigned long long)m) - 1) : 0;

    const size_t row = (size_t)b * NG + tg;
    const float4 gbox = *(const float4*)(gt + row * 4);
    const float bx1 = gbox.x, by1 = gbox.y, bx2 = gbox.z, by2 = gbox.w;
    const float pro = gt_pro[row];
    const float alp = gt_alp[row];

    // _batched_iou(gt, pd): clipped areas, union + 1e-9
    float iou_pd = 0.0f;
    if (fgb) {
        const float* P = pd + ((size_t)b * NA + a) * 4;
        float px1 = P[0], py1 = P[1], px2 = P[2], py2 = P[3];
        float w = fminf(bx2, px2) - fmaxf(bx1, px1); w = fmaxf(w, 0.0f);
        float h = fminf(by2, py2) - fmaxf(by1, py1); h = fmaxf(h, 0.0f);
        float ov = w * h;
        float a1 = fmaxf(bx2 - bx1, 0.0f) * fmaxf(by2 - by1, 0.0f);
        float a2 = fmaxf(px2 - px1, 0.0f) * fmaxf(py2 - py1, 0.0f);
        iou_pd = ov / (a1 + a2 - ov + 1e-9f);
    }

    out[t]       = fgb ? pro : (float)NPRO;
    out[S0 + t]  = fgb ? alp : (float)NALP;
    unsigned long long packed = ((unsigned long long)(unsigned)(int)pro) |
                                (((unsigned long long)(unsigned)(int)alp) << 8);
    #pragma unroll
    for (int i = 0; i < 6; ++i) {
        float av = gt_ads[row * 6 + i];
        out[(size_t)S0 * (2 + i) + t] = fgb ? av : (float)NADS;
        packed |= ((unsigned long long)(unsigned)(int)av) << (8 * (2 + i));
    }
    *(float4*)(out + (size_t)S0 * 8 + (size_t)t * 4) = gbox;
    {
        const float4* cn = (const float4*)(gt_cn + row * 8);
        float4* oc = (float4*)(out + (size_t)S0 * 12 + (size_t)t * 8);
        oc[0] = cn[0]; oc[1] = cn[1];
    }
    out[(size_t)S0 * 297 + t] = fgb ? 1.0f : 0.0f;

    iou_fg[t] = fgb ? iou_pd : 0.0f;
    cls8[t] = packed;
}

// Kernel 3: dense float4 streaming writer for the one-hot*iou score region
// (S0*277 floats starting at out + S0*20). Pure write-bound.
template <int NC>
__device__ __forceinline__ float4 score4(size_t fin,
                                         const unsigned long long* __restrict__ cls8,
                                         const float* __restrict__ iouv,
                                         int byteIdx) {
    unsigned t = (unsigned)(fin / NC);
    unsigned c = (unsigned)(fin - (size_t)t * NC);
    float4 v;
    float* pv = &v.x;
    unsigned tj = t, cj = c;
    #pragma unroll
    for (int j = 0; j < 4; ++j) {
        unsigned cls = (unsigned)((cls8[tj] >> (8 * byteIdx)) & 0xFFull);
        pv[j] = (cj == cls) ? iouv[tj] : 0.0f;
        ++cj; if (cj == NC) { cj = 0; ++tj; }
    }
    return v;
}

__global__ __launch_bounds__(256) void k_scores(
    const unsigned long long* __restrict__ cls8,
    const float* __restrict__ iouv,
    float* __restrict__ score)  // = out + S0*20
{
    const size_t TOT4 = (size_t)S0 * 277 / 4;      // 18,614,400
    size_t idx = (size_t)blockIdx.x * 256 + threadIdx.x;
    if (idx >= TOT4) return;
    size_t f = idx * 4;
    const size_t PRO_END = (size_t)S0 * NPRO;              // 8,332,800
    const size_t ALP_END = PRO_END + (size_t)S0 * NALP;    // 14,784,000
    const size_t ADS_SZ  = (size_t)S0 * NADS;              // 9,945,600
    float4 v;
    if (f < PRO_END) {
        v = score4<NPRO>(f, cls8, iouv, 0);
    } else if (f < ALP_END) {
        v = score4<NALP>(f - PRO_END, cls8, iouv, 1);
    } else {
        size_t r = f - ALP_END;
        int p = (int)(r / ADS_SZ);
        size_t rp = r - (size_t)p * ADS_SZ;
        v = score4<NADS>(rp, cls8, iouv, 2 + p);
    }
    *(float4*)(score + f) = v;
}

extern "C" void kernel_launch(void* const* d_in, const int* in_sizes, int n_in,
                              void* d_out, int out_size, void* d_ws, size_t ws_size,
                              hipStream_t stream) {
    const float* anc    = (const float*)d_in[0];
    const float* gt_pro = (const float*)d_in[2];
    const float* gt_alp = (const float*)d_in[3];
    const float* gt_ads = (const float*)d_in[4];
    const float* gt_bb  = (const float*)d_in[5];
    const float* gt_cn  = (const float*)d_in[6];
    const float* mgt    = (const float*)d_in[7];
    const float* pd     = (const float*)d_in[8];

    char* ws = (char*)d_ws;
    unsigned long long* gbits = (unsigned long long*)ws;                 // S0*8 B
    float* iou_fg             = (float*)(ws + (size_t)S0 * 8);           // S0*4 B
    unsigned long long* cls8  = (unsigned long long*)(ws + (size_t)S0 * 12); // S0*8 B
    float* out = (float*)d_out;

    hipLaunchKernelGGL(k_zero_gbits, dim3((S0 + 255) / 256), dim3(256), 0, stream, gbits);
    hipLaunchKernelGGL(k_cand, dim3(NB * NG), dim3(256), 0, stream,
                       anc, gt_bb, mgt, gbits);
    hipLaunchKernelGGL(k_assign, dim3((S0 + 255) / 256), dim3(256), 0, stream,
                       anc, gt_pro, gt_alp, gt_ads, gt_bb, gt_cn, pd, gbits,
                       iou_fg, cls8, out);
    const size_t TOT4 = (size_t)S0 * 277 / 4;
    hipLaunchKernelGGL(k_scores, dim3((unsigned)((TOT4 + 255) / 256)), dim3(256), 0, stream,
                       cls8, iou_fg, out + (size_t)S0 * 20);
}

// Round 4
// 519.593 us; speedup vs baseline: 1.0037x; 1.0037x over previous
//
#include <hip/hip_runtime.h>
#include <hip/hip_bf16.h>

#pragma clang fp contract(off)

#define NB 8
#define NG 64
#define NA 33600
#define KTOP 9
#define NCAND 27
#define NPRO 31
#define NALP 24
#define NADS 37
#define S0 268800  // NB*NA

typedef float vf4 __attribute__((ext_vector_type(4)));

// _pairwise_iou semantics: unclipped areas, union = max(a1+a2-ov, 1e-6)
__device__ __forceinline__ float pair_iou(float x1, float y1, float x2, float y2,
                                          float ax1, float ay1, float ax2, float ay2) {
    float a1 = (x2 - x1) * (y2 - y1);
    float a2 = (ax2 - ax1) * (ay2 - ay1);
    float w = fminf(x2, ax2) - fmaxf(x1, ax1); w = fmaxf(w, 0.0f);
    float h = fminf(y2, ay2) - fmaxf(y1, ay1); h = fmaxf(h, 0.0f);
    float ov = w * h;
    float un = a1 + a2 - ov; un = fmaxf(un, 1e-6f);
    return ov / un;
}

__global__ __launch_bounds__(256) void k_zero_gbits(unsigned long long* __restrict__ g) {
    int t = blockIdx.x * 256 + threadIdx.x;
    if (t < S0) g[t] = 0ull;
}

// Kernel 1: one block per (b,g). Top-9 per level by (distance, index) lex order,
// ATSS threshold, set bit g in gbits[b*NA + a] for each positive anchor.
__global__ __launch_bounds__(256) void k_cand(
    const float* __restrict__ anc,     // NA x 4
    const float* __restrict__ gt,      // NB x NG x 4
    const float* __restrict__ mgt,     // NB x NG
    unsigned long long* __restrict__ gbits) // NB x NA
{
    int bg = blockIdx.x;
    int b = bg >> 6;
    int g = bg & 63;
    if (mgt[bg] <= 0.0f) return;

    const float x1 = gt[bg * 4 + 0], y1 = gt[bg * 4 + 1];
    const float x2 = gt[bg * 4 + 2], y2 = gt[bg * 4 + 3];
    const float gx = (x1 + x2) * 0.5f, gy = (y1 + y2) * 0.5f;

    __shared__ float sd[256][KTOP];
    __shared__ int   si[256][KTOP];
    __shared__ int   cand[NCAND];

    const int tid = threadIdx.x;
    const int starts[3] = {0, 25600, 32000};
    const int lens[3]   = {25600, 6400, 1600};

    for (int lev = 0; lev < 3; ++lev) {
        float d9[KTOP]; int i9[KTOP];
        #pragma unroll
        for (int j = 0; j < KTOP; ++j) { d9[j] = INFINITY; i9[j] = 0x7fffffff; }

        const int s = starts[lev], L = lens[lev];
        for (int li = tid; li < L; li += 256) {
            int a = s + li;
            float ax = (anc[a * 4 + 0] + anc[a * 4 + 2]) * 0.5f;
            float ay = (anc[a * 4 + 1] + anc[a * 4 + 3]) * 0.5f;
            float dx = gx - ax, dy = gy - ay;
            float d = sqrtf(dx * dx + dy * dy);
            if (d < d9[KTOP - 1] || (d == d9[KTOP - 1] && li < i9[KTOP - 1])) {
                int j = KTOP - 1;
                while (j > 0 && (d < d9[j - 1] || (d == d9[j - 1] && li < i9[j - 1]))) {
                    d9[j] = d9[j - 1]; i9[j] = i9[j - 1]; --j;
                }
                d9[j] = d; i9[j] = li;
            }
        }

        for (int off = 128; off >= 1; off >>= 1) {
            #pragma unroll
            for (int j = 0; j < KTOP; ++j) { sd[tid][j] = d9[j]; si[tid][j] = i9[j]; }
            __syncthreads();
            if (tid < off) {
                float md[KTOP]; int mi[KTOP];
                int p = 0, q = 0;
                #pragma unroll
                for (int j = 0; j < KTOP; ++j) {
                    float da = d9[p];            int ia = i9[p];
                    float db = sd[tid + off][q]; int ib = si[tid + off][q];
                    bool takeA = (da < db) || (da == db && ia <= ib);
                    if (takeA) { md[j] = da; mi[j] = ia; ++p; }
                    else       { md[j] = db; mi[j] = ib; ++q; }
                }
                #pragma unroll
                for (int j = 0; j < KTOP; ++j) { d9[j] = md[j]; i9[j] = mi[j]; }
            }
            __syncthreads();
        }
        if (tid == 0) {
            #pragma unroll
            for (int j = 0; j < KTOP; ++j) cand[lev * KTOP + j] = s + i9[j];
        }
        __syncthreads();
    }

    if (tid == 0) {
        float co[NCAND];
        float sum = 0.0f;
        for (int j = 0; j < NCAND; ++j) {
            int a = cand[j];
            co[j] = pair_iou(x1, y1, x2, y2,
                             anc[a * 4 + 0], anc[a * 4 + 1], anc[a * 4 + 2], anc[a * 4 + 3]);
            sum += co[j];
        }
        float m = sum / 27.0f;
        float v = 0.0f;
        for (int j = 0; j < NCAND; ++j) { float dd = co[j] - m; v += dd * dd; }
        float thr = m + sqrtf(v / 26.0f);  // ddof=1
        for (int j = 0; j < NCAND; ++j) {
            if (co[j] > thr) {
                int a = cand[j];
                float ax = (anc[a * 4 + 0] + anc[a * 4 + 2]) * 0.5f;
                float ay = (anc[a * 4 + 1] + anc[a * 4 + 3]) * 0.5f;
                float mn = fminf(fminf(ax - x1, ay - y1), fminf(x2 - ax, y2 - ay));
                if (mn > 1e-9f) {
                    atomicOr(&gbits[(unsigned long long)b * NA + a], 1ull << g);
                }
            }
        }
    }
}

// Kernel 2: one thread per (b,anchor). Resolve multi-assignment, write the 20
// target planes + fg plane densely (nontemporal), emit (iou*fg, packed cls).
__global__ __launch_bounds__(256) void k_assign(
    const float* __restrict__ anc,
    const float* __restrict__ gt_pro,
    const float* __restrict__ gt_alp,
    const float* __restrict__ gt_ads,
    const float* __restrict__ gt,
    const float* __restrict__ gt_cn,
    const float* __restrict__ pd,
    const unsigned long long* __restrict__ gbits,
    float* __restrict__ iou_fg,            // S0
    unsigned long long* __restrict__ cls8, // S0
    float* __restrict__ out)
{
    const int t = blockIdx.x * 256 + threadIdx.x;
    if (t >= S0) return;
    const int b = t / NA;
    const int a = t - b * NA;

    unsigned long long m = gbits[t];
    if (__popcll(m) > 1) {
        float ax1 = anc[a * 4 + 0], ay1 = anc[a * 4 + 1];
        float ax2 = anc[a * 4 + 2], ay2 = anc[a * 4 + 3];
        float aarea = (ax2 - ax1) * (ay2 - ay1);
        float best = -INFINITY; int bgi = 0;
        for (int g = 0; g < NG; ++g) {
            const float* G = gt + ((size_t)b * NG + g) * 4;
            float gx1 = G[0], gy1 = G[1], gx2 = G[2], gy2 = G[3];
            float a1 = (gx2 - gx1) * (gy2 - gy1);
            float w = fminf(gx2, ax2) - fmaxf(gx1, ax1); w = fmaxf(w, 0.0f);
            float h = fminf(gy2, ay2) - fmaxf(gy1, ay1); h = fmaxf(h, 0.0f);
            float ov = w * h;
            float un = a1 + aarea - ov; un = fmaxf(un, 1e-6f);
            float iou = ov / un;
            if (iou > best) { best = iou; bgi = g; }
        }
        m = 1ull << bgi;
    }
    const bool fgb = (m != 0ull);
    const int tg = fgb ? (__ffsll((unsigned long long)m) - 1) : 0;

    const size_t row = (size_t)b * NG + tg;
    const vf4 gbox = *(const vf4*)(gt + row * 4);
    const float bx1 = gbox.x, by1 = gbox.y, bx2 = gbox.z, by2 = gbox.w;
    const float pro = gt_pro[row];
    const float alp = gt_alp[row];

    // _batched_iou(gt, pd): clipped areas, union + 1e-9
    float iou_pd = 0.0f;
    if (fgb) {
        const float* P = pd + ((size_t)b * NA + a) * 4;
        float px1 = P[0], py1 = P[1], px2 = P[2], py2 = P[3];
        float w = fminf(bx2, px2) - fmaxf(bx1, px1); w = fmaxf(w, 0.0f);
        float h = fminf(by2, py2) - fmaxf(by1, py1); h = fmaxf(h, 0.0f);
        float ov = w * h;
        float a1 = fmaxf(bx2 - bx1, 0.0f) * fmaxf(by2 - by1, 0.0f);
        float a2 = fmaxf(px2 - px1, 0.0f) * fmaxf(py2 - py1, 0.0f);
        iou_pd = ov / (a1 + a2 - ov + 1e-9f);
    }

    __builtin_nontemporal_store(fgb ? pro : (float)NPRO, out + t);
    __builtin_nontemporal_store(fgb ? alp : (float)NALP, out + S0 + t);
    unsigned long long packed = ((unsigned long long)(unsigned)(int)pro) |
                                (((unsigned long long)(unsigned)(int)alp) << 8);
    #pragma unroll
    for (int i = 0; i < 6; ++i) {
        float av = gt_ads[row * 6 + i];
        __builtin_nontemporal_store(fgb ? av : (float)NADS, out + (size_t)S0 * (2 + i) + t);
        packed |= ((unsigned long long)(unsigned)(int)av) << (8 * (2 + i));
    }
    __builtin_nontemporal_store(gbox, (vf4*)(out + (size_t)S0 * 8 + (size_t)t * 4));
    {
        const vf4* cn = (const vf4*)(gt_cn + row * 8);
        vf4* oc = (vf4*)(out + (size_t)S0 * 12 + (size_t)t * 8);
        __builtin_nontemporal_store(cn[0], oc);
        __builtin_nontemporal_store(cn[1], oc + 1);
    }
    __builtin_nontemporal_store(fgb ? 1.0f : 0.0f, out + (size_t)S0 * 297 + t);

    iou_fg[t] = fgb ? iou_pd : 0.0f;
    cls8[t] = packed;
}

// Kernel 3 family: dense float4 streaming writers, one instantiation per
// region. Pure 32-bit index math; NC compile-time so /NC and %NC become
// magic-mul. blockIdx.y = ads plane (byteIdx = 2+y).
template <int NC, int BYTE_BASE, bool USE_Y>
__global__ __launch_bounds__(256) void k_scores_t(
    const unsigned long long* __restrict__ cls8,
    const float* __restrict__ iouv,
    float* __restrict__ base)  // region base (plane 0 if USE_Y)
{
    const unsigned PLANE = (unsigned)S0 * NC;
    unsigned idx = blockIdx.x * 256u + threadIdx.x;
    unsigned f = idx * 4u;
    if (f >= PLANE) return;
    float* plane = USE_Y ? (base + (size_t)blockIdx.y * PLANE) : base;
    const int byteIdx = USE_Y ? (BYTE_BASE + (int)blockIdx.y) : BYTE_BASE;

    unsigned t = f / NC;
    unsigned c = f - t * NC;
    vf4 v;
    unsigned cls = (unsigned)((cls8[t] >> (8 * byteIdx)) & 0xFFull);
    float iou = iouv[t];
    #pragma unroll
    for (int j = 0; j < 4; ++j) {
        v[j] = (c == cls) ? iou : 0.0f;
        ++c;
        if (c == NC) { c = 0; ++t; cls = (unsigned)((cls8[t] >> (8 * byteIdx)) & 0xFFull); iou = iouv[t]; }
    }
    __builtin_nontemporal_store(v, (vf4*)(plane + f));
}

extern "C" void kernel_launch(void* const* d_in, const int* in_sizes, int n_in,
                              void* d_out, int out_size, void* d_ws, size_t ws_size,
                              hipStream_t stream) {
    const float* anc    = (const float*)d_in[0];
    const float* gt_pro = (const float*)d_in[2];
    const float* gt_alp = (const float*)d_in[3];
    const float* gt_ads = (const float*)d_in[4];
    const float* gt_bb  = (const float*)d_in[5];
    const float* gt_cn  = (const float*)d_in[6];
    const float* mgt    = (const float*)d_in[7];
    const float* pd     = (const float*)d_in[8];

    char* ws = (char*)d_ws;
    unsigned long long* gbits = (unsigned long long*)ws;                     // S0*8 B
    float* iou_fg             = (float*)(ws + (size_t)S0 * 8);               // S0*4 B
    unsigned long long* cls8  = (unsigned long long*)(ws + (size_t)S0 * 16); // S0*8 B (16-align)
    float* out = (float*)d_out;

    hipLaunchKernelGGL(k_zero_gbits, dim3((S0 + 255) / 256), dim3(256), 0, stream, gbits);
    hipLaunchKernelGGL(k_cand, dim3(NB * NG), dim3(256), 0, stream,
                       anc, gt_bb, mgt, gbits);
    hipLaunchKernelGGL(k_assign, dim3((S0 + 255) / 256), dim3(256), 0, stream,
                       anc, gt_pro, gt_alp, gt_ads, gt_bb, gt_cn, pd, gbits,
                       iou_fg, cls8, out);

    float* score = out + (size_t)S0 * 20;
    // pro: S0*31 floats
    {
        unsigned n4 = (unsigned)S0 * NPRO / 4;
        hipLaunchKernelGGL((k_scores_t<NPRO, 0, false>), dim3((n4 + 255) / 256), dim3(256),
                           0, stream, cls8, iou_fg, score);
    }
    // alp: S0*24 floats
    {
        unsigned n4 = (unsigned)S0 * NALP / 4;
        hipLaunchKernelGGL((k_scores_t<NALP, 1, false>), dim3((n4 + 255) / 256), dim3(256),
                           0, stream, cls8, iou_fg, score + (size_t)S0 * NPRO);
    }
    // ads: 6 planes of S0*37 floats
    {
        unsigned n4 = (unsigned)S0 * NADS / 4;
        hipLaunchKernelGGL((k_scores_t<NADS, 2, true>), dim3((n4 + 255) / 256, 6), dim3(256),
                           0, stream, cls8, iou_fg,
                           score + (size_t)S0 * (NPRO + NALP));
    }
}

// Round 5
// 433.989 us; speedup vs baseline: 1.2017x; 1.1972x over previous
//
#include <hip/hip_runtime.h>
#include <hip/hip_bf16.h>

#pragma clang fp contract(off)

#define NB 8
#define NG 64
#define NA 33600
#define KTOP 9
#define NCAND 27
#define NPRO 31
#define NALP 24
#define NADS 37
#define S0 268800  // NB*NA

typedef float vf4 __attribute__((ext_vector_type(4)));

// _pairwise_iou semantics: unclipped areas, union = max(a1+a2-ov, 1e-6)
__device__ __forceinline__ float pair_iou(float x1, float y1, float x2, float y2,
                                          float ax1, float ay1, float ax2, float ay2) {
    float a1 = (x2 - x1) * (y2 - y1);
    float a2 = (ax2 - ax1) * (ay2 - ay1);
    float w = fminf(x2, ax2) - fmaxf(x1, ax1); w = fmaxf(w, 0.0f);
    float h = fminf(y2, ay2) - fmaxf(y1, ay1); h = fmaxf(h, 0.0f);
    float ov = w * h;
    float un = a1 + a2 - ov; un = fmaxf(un, 1e-6f);
    return ov / un;
}

// Kernel 1: one THREAD per (b,g). Anchors form regular grids, so the top-9
// nearest centers per level lie inside the 7x7 cell window around the gt
// center (9th-nearest <= ~2.12 cells < 2.5). Enumerate in increasing index
// order, keep sorted top-9 by (d, idx) lex — identical to stable lax.top_k.
__global__ __launch_bounds__(256) void k_cand2(
    const float* __restrict__ anc,     // NA x 4 (for IoU phase)
    const float* __restrict__ gt,      // NB x NG x 4
    const float* __restrict__ mgt,     // NB x NG
    unsigned long long* __restrict__ gbits) // NB x NA
{
    const int t = blockIdx.x * 256 + threadIdx.x;
    if (t >= NB * NG) return;
    const int b = t >> 6;
    const int g = t & 63;
    if (mgt[t] <= 0.0f) return;

    const float x1 = gt[t * 4 + 0], y1 = gt[t * 4 + 1];
    const float x2 = gt[t * 4 + 2], y2 = gt[t * 4 + 3];
    const float gx = (x1 + x2) * 0.5f, gy = (y1 + y2) * 0.5f;

    int cand[NCAND];

    const int   ns[3] = {160, 80, 40};
    const float ss[3] = {8.0f, 16.0f, 32.0f};
    const int   st[3] = {0, 25600, 32000};

    #pragma unroll
    for (int lev = 0; lev < 3; ++lev) {
        const int n = ns[lev];
        const float s = ss[lev];
        int ixn = (int)floorf(gx / s);
        int iyn = (int)floorf(gy / s);
        int xlo = min(max(ixn - 3, 0), n - 7);
        int ylo = min(max(iyn - 3, 0), n - 7);

        float d9[KTOP]; int i9[KTOP];
        #pragma unroll
        for (int j = 0; j < KTOP; ++j) { d9[j] = INFINITY; i9[j] = 0x7fffffff; }

        for (int dy = 0; dy < 7; ++dy) {
            int iy = ylo + dy;
            float ay = ((float)iy + 0.5f) * s;
            float ddy = gy - ay;
            for (int dx = 0; dx < 7; ++dx) {
                int ix = xlo + dx;
                float ax = ((float)ix + 0.5f) * s;
                float ddx = gx - ax;
                float d = sqrtf(ddx * ddx + ddy * ddy);
                int li = iy * n + ix;
                if (d < d9[KTOP - 1] || (d == d9[KTOP - 1] && li < i9[KTOP - 1])) {
                    d9[KTOP - 1] = d; i9[KTOP - 1] = li;
                    #pragma unroll
                    for (int j = KTOP - 1; j > 0; --j) {
                        bool sw = (d9[j] < d9[j - 1]) ||
                                  (d9[j] == d9[j - 1] && i9[j] < i9[j - 1]);
                        if (sw) {
                            float td = d9[j]; d9[j] = d9[j - 1]; d9[j - 1] = td;
                            int   ti = i9[j]; i9[j] = i9[j - 1]; i9[j - 1] = ti;
                        }
                    }
                }
            }
        }
        #pragma unroll
        for (int j = 0; j < KTOP; ++j) cand[lev * KTOP + j] = st[lev] + i9[j];
    }

    float co[NCAND];
    float sum = 0.0f;
    #pragma unroll
    for (int j = 0; j < NCAND; ++j) {
        int a = cand[j];
        co[j] = pair_iou(x1, y1, x2, y2,
                         anc[a * 4 + 0], anc[a * 4 + 1], anc[a * 4 + 2], anc[a * 4 + 3]);
        sum += co[j];
    }
    float m = sum / 27.0f;
    float v = 0.0f;
    #pragma unroll
    for (int j = 0; j < NCAND; ++j) { float dd = co[j] - m; v += dd * dd; }
    float thr = m + sqrtf(v / 26.0f);  // ddof=1
    #pragma unroll
    for (int j = 0; j < NCAND; ++j) {
        if (co[j] > thr) {
            int a = cand[j];
            float ax = (anc[a * 4 + 0] + anc[a * 4 + 2]) * 0.5f;
            float ay = (anc[a * 4 + 1] + anc[a * 4 + 3]) * 0.5f;
            float mn = fminf(fminf(ax - x1, ay - y1), fminf(x2 - ax, y2 - ay));
            if (mn > 1e-9f) {
                atomicOr(&gbits[(unsigned long long)b * NA + a], 1ull << g);
            }
        }
    }
}

// Kernel 2: one thread per (b,anchor). Resolve multi-assignment via argmax
// overlap, write the 20 target planes + fg plane densely (nontemporal),
// sparse-scatter one-hot*iou scores into the pre-zeroed score region.
__global__ __launch_bounds__(256) void k_assign(
    const float* __restrict__ anc,
    const float* __restrict__ gt_pro,
    const float* __restrict__ gt_alp,
    const float* __restrict__ gt_ads,
    const float* __restrict__ gt,
    const float* __restrict__ gt_cn,
    const float* __restrict__ pd,
    const unsigned long long* __restrict__ gbits,
    float* __restrict__ out)
{
    const int t = blockIdx.x * 256 + threadIdx.x;
    if (t >= S0) return;
    const int b = t / NA;
    const int a = t - b * NA;

    unsigned long long m = gbits[t];
    if (__popcll(m) > 1) {
        float ax1 = anc[a * 4 + 0], ay1 = anc[a * 4 + 1];
        float ax2 = anc[a * 4 + 2], ay2 = anc[a * 4 + 3];
        float aarea = (ax2 - ax1) * (ay2 - ay1);
        float best = -INFINITY; int bgi = 0;
        for (int g = 0; g < NG; ++g) {
            const float* G = gt + ((size_t)b * NG + g) * 4;
            float gx1 = G[0], gy1 = G[1], gx2 = G[2], gy2 = G[3];
            float a1 = (gx2 - gx1) * (gy2 - gy1);
            float w = fminf(gx2, ax2) - fmaxf(gx1, ax1); w = fmaxf(w, 0.0f);
            float h = fminf(gy2, ay2) - fmaxf(gy1, ay1); h = fmaxf(h, 0.0f);
            float ov = w * h;
            float un = a1 + aarea - ov; un = fmaxf(un, 1e-6f);
            float iou = ov / un;
            if (iou > best) { best = iou; bgi = g; }
        }
        m = 1ull << bgi;
    }
    const bool fgb = (m != 0ull);
    const int tg = fgb ? (__ffsll((unsigned long long)m) - 1) : 0;

    const size_t row = (size_t)b * NG + tg;
    const vf4 gbox = *(const vf4*)(gt + row * 4);
    const float bx1 = gbox.x, by1 = gbox.y, bx2 = gbox.z, by2 = gbox.w;
    const float pro = gt_pro[row];
    const float alp = gt_alp[row];

    // _batched_iou(gt, pd): clipped areas, union + 1e-9
    float iou_pd = 0.0f;
    if (fgb) {
        const float* P = pd + ((size_t)b * NA + a) * 4;
        float px1 = P[0], py1 = P[1], px2 = P[2], py2 = P[3];
        float w = fminf(bx2, px2) - fmaxf(bx1, px1); w = fmaxf(w, 0.0f);
        float h = fminf(by2, py2) - fmaxf(by1, py1); h = fmaxf(h, 0.0f);
        float ov = w * h;
        float a1 = fmaxf(bx2 - bx1, 0.0f) * fmaxf(by2 - by1, 0.0f);
        float a2 = fmaxf(px2 - px1, 0.0f) * fmaxf(py2 - py1, 0.0f);
        iou_pd = ov / (a1 + a2 - ov + 1e-9f);
    }

    __builtin_nontemporal_store(fgb ? pro : (float)NPRO, out + t);
    __builtin_nontemporal_store(fgb ? alp : (float)NALP, out + S0 + t);
    float adsv[6];
    #pragma unroll
    for (int i = 0; i < 6; ++i) {
        adsv[i] = gt_ads[row * 6 + i];
        __builtin_nontemporal_store(fgb ? adsv[i] : (float)NADS, out + (size_t)S0 * (2 + i) + t);
    }
    __builtin_nontemporal_store(gbox, (vf4*)(out + (size_t)S0 * 8 + (size_t)t * 4));
    {
        const vf4* cn = (const vf4*)(gt_cn + row * 8);
        vf4* oc = (vf4*)(out + (size_t)S0 * 12 + (size_t)t * 8);
        __builtin_nontemporal_store(cn[0], oc);
        __builtin_nontemporal_store(cn[1], oc + 1);
    }
    __builtin_nontemporal_store(fgb ? 1.0f : 0.0f, out + (size_t)S0 * 297 + t);

    // sparse score scatter into pre-zeroed region
    if (fgb) {
        out[(size_t)S0 * 20 + (size_t)t * NPRO + (int)pro] = iou_pd;
        out[(size_t)S0 * 20 + (size_t)S0 * NPRO + (size_t)t * NALP + (int)alp] = iou_pd;
        const size_t ads_base = (size_t)S0 * 20 + (size_t)S0 * NPRO + (size_t)S0 * NALP;
        #pragma unroll
        for (int i = 0; i < 6; ++i) {
            out[ads_base + (size_t)i * S0 * NADS + (size_t)t * NADS + (int)adsv[i]] = iou_pd;
        }
    }
}

extern "C" void kernel_launch(void* const* d_in, const int* in_sizes, int n_in,
                              void* d_out, int out_size, void* d_ws, size_t ws_size,
                              hipStream_t stream) {
    const float* anc    = (const float*)d_in[0];
    const float* gt_pro = (const float*)d_in[2];
    const float* gt_alp = (const float*)d_in[3];
    const float* gt_ads = (const float*)d_in[4];
    const float* gt_bb  = (const float*)d_in[5];
    const float* gt_cn  = (const float*)d_in[6];
    const float* mgt    = (const float*)d_in[7];
    const float* pd     = (const float*)d_in[8];

    unsigned long long* gbits = (unsigned long long*)d_ws;
    float* out = (float*)d_out;

    // zero the gt-bitmask workspace (2.15 MB) and the score region (297.9 MB).
    hipMemsetAsync(gbits, 0, (size_t)S0 * 8, stream);
    hipMemsetAsync(out + (size_t)S0 * 20, 0, (size_t)S0 * 277 * sizeof(float), stream);

    hipLaunchKernelGGL(k_cand2, dim3((NB * NG + 255) / 256), dim3(256), 0, stream,
                       anc, gt_bb, mgt, gbits);
    hipLaunchKernelGGL(k_assign, dim3((S0 + 255) / 256), dim3(256), 0, stream,
                       anc, gt_pro, gt_alp, gt_ads, gt_bb, gt_cn, pd, gbits, out);
}